// Round 12
// baseline (37890.289 us; speedup 1.0000x reference)
//
#include <hip/hip_runtime.h>
#include <math.h>

static constexpr int T_STEPS = 10000;
static constexpr int I_DIM = 2048;
static constexpr int O_DIM = 512;
static constexpr int WGS = 1024;          // 16 waves, one CU
static constexpr int KPAD = 192;          // padded spike list (mean 102.4, sd 9.9)
static constexpr int NSPL = 6;            // gather residues (waves 4..15, 768 threads)
static constexpr int GN = 19;             // fixed async gather loads/thread (covers cnt<=114)
static constexpr float PSPD = 0.9512294245007140091f;  // exp(-0.001/0.02)
static constexpr float OUTD = 0.9048374180359595732f;  // exp(-0.001/0.01)
static constexpr float MU = 0.1f;

typedef float __attribute__((ext_vector_type(4))) f32x4;
typedef float __attribute__((ext_vector_type(2))) f32x2;

// ---------------- K1: compress spikes into ordered, PADDED index lists ----------------
__global__ void build_idx_kernel(const float* __restrict__ spikes,
                                 unsigned short* __restrict__ idxl,
                                 int* __restrict__ cnts) {
    int t = blockIdx.x;
    int tid = threadIdx.x;                 // 256 threads
    if (t >= T_STEPS) {                    // pad rows t = T .. T+3
        for (int p = tid; p < KPAD; p += 256) idxl[(size_t)t * KPAD + p] = (unsigned short)I_DIM;
        if (tid == 0) cnts[t] = 0;
        return;
    }
    const float4* row = reinterpret_cast<const float4*>(spikes + (size_t)t * I_DIM);
    float4 a = row[tid * 2];
    float4 b = row[tid * 2 + 1];
    float v[8] = {a.x, a.y, a.z, a.w, b.x, b.y, b.z, b.w};
    unsigned short tmp[8];
    int c = 0;
#pragma unroll
    for (int j = 0; j < 8; ++j)
        if (v[j] != 0.0f) tmp[c++] = (unsigned short)(tid * 8 + j);

    int lane = tid & 63, wid = tid >> 6;
    int x = c;
    for (int d = 1; d < 64; d <<= 1) {
        int y = __shfl_up(x, d);
        if (lane >= d) x += y;
    }
    __shared__ int wtot[4];
    if (lane == 63) wtot[wid] = x;
    __syncthreads();
    int off = x - c;
    for (int w = 0; w < wid; ++w) off += wtot[w];
    int tot = wtot[0] + wtot[1] + wtot[2] + wtot[3];
    if (tot > KPAD) tot = KPAD;
    for (int j = 0; j < c; ++j) {
        int p = off + j;
        if (p < KPAD) idxl[(size_t)t * KPAD + p] = tmp[j];
    }
    for (int p = tid; p < KPAD; p += 256)
        if (p >= tot) idxl[(size_t)t * KPAD + p] = (unsigned short)I_DIM;
    if (tid == 0) cnts[t] = tot;
}

// ---------------- K2a: copy W into mutable row-major workspace ----------------
__global__ void copy_w_kernel(const float* __restrict__ W, float* __restrict__ Wrow) {
    int i = blockIdx.x * blockDim.x + threadIdx.x;
    reinterpret_cast<float4*>(Wrow)[i] = reinterpret_cast<const float4*>(W)[i];
}

// ---------------- K2b: tiled transpose W[O][I] -> Wt[I][O] ----------------
__global__ void transpose_kernel(const float* __restrict__ W, float* __restrict__ Wt) {
    __shared__ float tile[32][33];
    int i0 = blockIdx.x * 32;
    int o0 = blockIdx.y * 32;
    int x = threadIdx.x;
    for (int y = threadIdx.y; y < 32; y += 8)
        tile[y][x] = W[(size_t)(o0 + y) * I_DIM + i0 + x];
    __syncthreads();
    for (int y = threadIdx.y; y < 32; y += 8)
        Wt[(size_t)(i0 + y) * O_DIM + o0 + x] = tile[x][y];
}

// ---------------- K2c: zero the pad row of Wt (row index I_DIM) ----------------
__global__ void zero_pad_row_kernel(float* __restrict__ Wt) {
    Wt[(size_t)I_DIM * O_DIM + threadIdx.x] = 0.0f;
}

// light barrier: LDS-drain only; global loads stay in flight
__device__ __forceinline__ void bar() {
    asm volatile("s_waitcnt lgkmcnt(0)" ::: "memory");
    __builtin_amdgcn_sched_barrier(0);
    __builtin_amdgcn_s_barrier();
    __builtin_amdgcn_sched_barrier(0);
}

// wave64 max, uniform result (max associative -> tree bitwise-safe)
__device__ __forceinline__ float wave_max_dpp(float x) {
    int xb = __float_as_int(x);
#define DPPSTEPM(ctrl, rm)                                                          \
    {                                                                               \
        int tt = __builtin_amdgcn_update_dpp(0xff800000, xb, ctrl, rm, 0xf, false); \
        xb = __float_as_int(fmaxf(__int_as_float(xb), __int_as_float(tt)));         \
    }
    DPPSTEPM(0x111, 0xf)
    DPPSTEPM(0x112, 0xf)
    DPPSTEPM(0x114, 0xf)
    DPPSTEPM(0x118, 0xf)
    DPPSTEPM(0x142, 0xa)
    DPPSTEPM(0x143, 0xc)
#undef DPPSTEPM
    return __int_as_float(__builtin_amdgcn_readlane(xb, 63));
}

// wave64 inclusive prefix sum (per-lane); lane63 = wave total
__device__ __forceinline__ float dpp_scan_add(float x) {
#define DPPSTEPA(ctrl, rm)                                                          \
    {                                                                               \
        float tt = __int_as_float(                                                  \
            __builtin_amdgcn_update_dpp(0, __float_as_int(x), ctrl, rm, 0xf, false)); \
        x += tt;                                                                    \
    }
    DPPSTEPA(0x111, 0xf)
    DPPSTEPA(0x112, 0xf)
    DPPSTEPA(0x114, 0xf)
    DPPSTEPA(0x118, 0xf)
    DPPSTEPA(0x142, 0xa)
    DPPSTEPA(0x143, 0xc)
#undef DPPSTEPA
    return x;
}

// ---------------- K3: single workgroup; waves 0-3 softmax stripes, 4-15 gather ----------------
__launch_bounds__(WGS, 1)
__global__ void seq_kernel(const unsigned short* __restrict__ idxl,
                           const int* __restrict__ cnts,
                           const float* __restrict__ u_rand,
                           const float* __restrict__ b_in,
                           float* __restrict__ Wrow,
                           float* __restrict__ Wt,
                           float* __restrict__ out) {
    __shared__ __align__(16) float psp[I_DIM + 4];
    __shared__ __align__(16) float mk0[I_DIM + 4];   // spike masks, parity double buffer
    __shared__ __align__(16) float mk1[I_DIM + 4];
    __shared__ f32x4 sg[2][NSPL][128];               // double-buffered residue partials
    __shared__ float redE[16], redF[16], redG[2][16];
    __shared__ float redM[4], redS[4];               // per-stripe softmax pieces
    __shared__ __align__(16) unsigned short sidx[3][KPAD];  // 3-deep rotation (R8)
    __shared__ int s_rr;

    const int tid = threadIdx.x;
    const int lane = tid & 63;
    const int jw = tid >> 6;                         // 0..3 softmax, 4..15 gather
    const int i2 = tid * 2;
    const int gt = tid - 256;                        // gather-thread index
    const int r = gt >> 7;                           // residue 0..5 (tid>=256)
    const int g = gt & 127;                          // f32x4 slot within a column
    const f32x4* __restrict__ Wt4 = reinterpret_cast<const f32x4*>(Wt);
    const unsigned long long wt_base = (unsigned long long)Wt;

    // ---------------- prologue ----------------
    for (int p = tid; p < I_DIM + 4; p += WGS) { psp[p] = 0.0f; mk0[p] = 0.0f; mk1[p] = 0.0f; }
    if (tid < 3 * KPAD) ((unsigned short*)sidx)[tid] = idxl[tid];   // lists 0..2
    if (tid < 16) { redE[tid] = 0.0f; redF[tid] = 0.0f; }
    if (tid < 32) redG[tid >> 4][tid & 15] = 0.0f;
    if (tid < 4) { redM[tid] = 0.0f; redS[tid] = 0.0f; }
    if (tid == 0) s_rr = O_DIM - 1;
    __syncthreads();
    const int cnt0 = cnts[0];
    if (tid < KPAD) {
        psp[sidx[0][tid]] = 1.0f;                    // psp(0) = s_0 (pads -> dead slot)
        mk1[sidx[1][tid]] = 1.0f;                    // mask of s_1
    }
    __syncthreads();
    if (tid >= 256) {                                // synchronous gather of G(0), 6-way
        f32x4 acc = {0.0f, 0.0f, 0.0f, 0.0f};
        for (int k = r; k < cnt0; k += NSPL)
            acc += Wt4[(size_t)sidx[0][k] * 128 + g];
        sg[0][r][g] = acc;
    }
    // softmax-wave persistent state (stripe w = jw, 2 outputs/lane)
    float aA0 = 0.0f, aA1 = 0.0f, b0 = 0.0f, b1 = 0.0f, tr0 = 0.0f, tr1 = 0.0f;
    if (jw < 4) { b0 = b_in[jw * 128 + 2 * lane]; b1 = b_in[jw * 128 + 2 * lane + 1]; }
    int col1 = 1 << 30, col2 = 1 << 30;
    float nw0 = 0.0f, nw1 = 0.0f;                    // persisted winning-row slice (2 cols)
    int cnt_use = cnts[1], cnt_fut = 0;
    float u_cur = u_rand[0], u_nxt = 0.0f;
    unsigned int pfw = 0;
    __syncthreads();

    for (int t = 0; t < T_STEPS; ++t) {
        const int par = t & 1, cb = par, nb = par ^ 1;
        float* mcur = par ? mk1 : mk0;               // cleared now; E scatters s_{t+2}
        float* mnxt = par ? mk0 : mk1;               // holds s_{t+1}

        // ================= P1: common chores =================
        f32x2 mreg = *(const f32x2*)(mnxt + i2);     // s_{t+1} slice
        {   // 2-deep correction source: W_{t-1}[rr(t-1)] . s_{t+1}
            float gp2 = nw0 * mreg.x + nw1 * mreg.y;
            float s2 = dpp_scan_add(gp2);
            if (lane == 63) redG[par][jw] = s2;
        }
        mcur[i2] = 0.0f; mcur[i2 + 1] = 0.0f;
        f32x2 pr = *(const f32x2*)(psp + i2);
        {
#pragma clang fp contract(off)
            float q0 = pr.x * PSPD; q0 += mreg.x;
            float q1 = pr.y * PSPD; q1 += mreg.y;
            psp[i2] = q0; psp[i2 + 1] = q1;
        }
        if (tid == 0) s_rr = O_DIM - 1;

        float e0 = 0.0f, e1 = 0.0f, pin = 0.0f, pex = 0.0f;
        if (tid >= 256) {
            // -------- gather engine: issue, drain, consume, stage --------
            {
                const int* cp = cnts + (t + 2);
                asm volatile("global_load_dword %0, %1, off" : "=&v"(cnt_fut) : "v"(cp) : "memory");
            }
            if (gt < KPAD / 2) {                     // stagers: tid 256..351 (R8 pattern)
                const unsigned int* pp = reinterpret_cast<const unsigned int*>(idxl) +
                                         (size_t)(t + 3) * (KPAD / 2) + gt;
                asm volatile("global_load_dword %0, %1, off" : "=&v"(pfw) : "v"(pp) : "memory");
            }
            f32x4 vals[GN];
            {
                const unsigned short* lst = sidx[(t + 1) % 3];
#pragma unroll
                for (int j = 0; j < GN; ++j) {
                    int col = lst[r + NSPL * j];
                    unsigned int voff = ((unsigned)col << 11) + ((unsigned)g << 4);
                    asm volatile("global_load_dwordx4 %0, %1, %2"
                                 : "=&v"(vals[j]) : "v"(voff), "s"(wt_base) : "memory");
                }
            }
            asm volatile("s_waitcnt vmcnt(0)" ::: "memory");
            __builtin_amdgcn_sched_barrier(0);
            asm volatile("" : "+v"(cnt_fut), "+v"(pfw));
            {
                f32x4 acc = vals[0];
#pragma unroll
                for (int j = 1; j < GN; ++j) acc += vals[j];
                if (cnt_use > NSPL * GN) {           // tail (cnt > 114, ~12% of steps)
                    const unsigned short* lst = sidx[(t + 1) % 3];
                    for (int k = NSPL * GN + r; k < cnt_use; k += NSPL)
                        acc += Wt4[(size_t)lst[k] * 128 + g];
                }
                sg[nb][r][g] = acc;                  // G(t+1)
            }
            if (gt < KPAD / 2)                       // land list(t+3)
                ((unsigned int*)sidx[(t + 3) % 3])[gt] = pfw;
        } else {
            // -------- softmax part 1 (stripe w = jw, R8 code) --------
            {
                int tu = t + 1; if (tu > T_STEPS - 1) tu = T_STEPS - 1;
                const float* up = u_rand + tu;
                asm volatile("global_load_dword %0, %1, off" : "=&v"(u_nxt) : "v"(up) : "memory");
            }
            tr0 *= OUTD; tr1 *= OUTD;
            float v0 = 0.0f, v1 = 0.0f;
#pragma unroll
            for (int r2 = 0; r2 < NSPL; ++r2) {
                const f32x2* sgc = reinterpret_cast<const f32x2*>(&sg[cb][r2][0]);
                f32x2 s2v = sgc[jw * 64 + lane];
                v0 += s2v.x; v1 += s2v.y;
            }
            if ((col1 >> 7) == jw) {                 // stale fixes for rr(t-1)
                float es = 0.0f, fs = 0.0f;
#pragma unroll
                for (int j = 0; j < 16; ++j) { es += redE[j]; fs += redF[j]; }
                int c1 = col1 & 127;
                if (lane == (c1 >> 1)) {
                    if (c1 & 1) { aA1 += es; v1 = fs; } else { aA0 += es; v0 = fs; }
                }
            }
            if (((col2 >> 7) == jw) && col2 != col1) {   // 2-deep fix for rr(t-2)
                float gs = 0.0f;
#pragma unroll
                for (int j = 0; j < 16; ++j) gs += redG[par ^ 1][j];
                int c2 = col2 & 127;
                if (lane == (c2 >> 1)) { if (c2 & 1) v1 = gs; else v0 = gs; }
            }
            aA0 = PSPD * aA0 + v0; aA1 = PSPD * aA1 + v1;
            float z0 = aA0 + b0, z1 = aA1 + b1;
            float m_w = wave_max_dpp(fmaxf(z0, z1));
            e0 = expf(z0 - m_w); e1 = expf(z1 - m_w);
            pin = dpp_scan_add(e0 + e1);
            pex = __int_as_float(
                __builtin_amdgcn_update_dpp(0, __float_as_int(pin), 0x111, 0xf, 0xf, false));
            float p15 = __int_as_float(__builtin_amdgcn_readlane(__float_as_int(pin), 15));
            float p31 = __int_as_float(__builtin_amdgcn_readlane(__float_as_int(pin), 31));
            float p47 = __int_as_float(__builtin_amdgcn_readlane(__float_as_int(pin), 47));
            if (lane == 16) pex = p15;
            if (lane == 32) pex = p31;
            if (lane == 48) pex = p47;
            float S_w = __int_as_float(__builtin_amdgcn_readlane(__float_as_int(pin), 63));
            if (lane == 0) { redM[jw] = m_w; redS[jw] = S_w; }
        }
        bar();  // B1a: per-stripe (m,S) visible

        // ================= combine + winner (softmax waves only, R8 chain) =================
        if (jw < 4) {
            float mj[4], sj[4];
#pragma unroll
            for (int j = 0; j < 4; ++j) { mj[j] = redM[j]; sj[j] = redS[j]; }
            float M = fmaxf(fmaxf(mj[0], mj[1]), fmaxf(mj[2], mj[3]));
            float o_run = 0.0f, offw = 0.0f, sc_w = 0.0f;
#pragma unroll
            for (int j = 0; j < 4; ++j) {            // identical chain in all 4 waves
                float sc = expf(mj[j] - M);
                if (j == jw) { offw = o_run; sc_w = sc; }
                o_run = fmaf(sj[j], sc, o_run);
            }
            float uQ = u_cur * o_run;                // numerator space (no divide)
            float cqp0 = fmaf(pex, sc_w, offw);
            float cq0  = fmaf(pex + e0, sc_w, offw);
            float cq1  = fmaf(pin, sc_w, offw);
            bool firstG = (jw == 0 && lane == 0);
            bool lastG  = (jw == 3 && lane == 63);
            bool w0c = (cqp0 < uQ || firstG) && (uQ <= cq0);
            bool w1c = (cq0 < uQ) && (uQ <= cq1 || lastG);
            if (w0c) atomicMin(&s_rr, jw * 128 + 2 * lane);
            if (w1c) atomicMin(&s_rr, jw * 128 + 2 * lane + 1);
            asm volatile("s_waitcnt vmcnt(0)" ::: "memory");   // u_nxt landed
            __builtin_amdgcn_sched_barrier(0);
            asm volatile("" : "+v"(u_nxt));
            u_cur = u_nxt;
        }
        bar();  // B1: winner visible

        // ================= E: row update (all 1024 threads, 2 cols each) =================
        const int rr = s_rr;
        f32x2 w2v;
        {
            const float* rp0 = Wrow + (size_t)rr * I_DIM + i2;
            asm volatile("global_load_dwordx2 %0, %1, off" : "=&v"(w2v) : "v"(rp0) : "memory");
        }
        if (tid < KPAD) mcur[sidx[(t + 2) % 3][tid]] = 1.0f;   // scatter s_{t+2}
        asm volatile("s_waitcnt vmcnt(0)" ::: "memory");       // w2 only outstanding
        __builtin_amdgcn_sched_barrier(0);
        nw0 = w2v.x + MU * (expf(-w2v.x) * pr.x - 1.0f);
        nw1 = w2v.y + MU * (expf(-w2v.y) * pr.y - 1.0f);
        *reinterpret_cast<float2*>(&Wrow[(size_t)rr * I_DIM + i2]) = make_float2(nw0, nw1);
        Wt[(size_t)i2 * O_DIM + rr] = nw0;
        Wt[(size_t)(i2 + 1) * O_DIM + rr] = nw1;
        {
            float dp = (nw0 - w2v.x) * pr.x + (nw1 - w2v.y) * pr.y;  // A[rr] correction
            float gp = nw0 * mreg.x + nw1 * mreg.y;                  // G(t+1)[rr] exact
            float sd = dpp_scan_add(dp);
            float sf = dpp_scan_add(gp);
            if (lane == 63) { redE[jw] = sd; redF[jw] = sf; }
        }
        if (jw == (rr >> 7) && lane == ((rr & 127) >> 1)) {
            if (rr & 1) { tr1 += 1.0f; b1 = b1 + MU * (expf(-b1) - 1.0f); }
            else        { tr0 += 1.0f; b0 = b0 + MU * (expf(-b0) - 1.0f); }
            out[(size_t)t * O_DIM + rr] = 1.0f;
        }
        col2 = col1; col1 = rr;
        cnt_use = cnt_fut;
        bar();  // B2
    }

    __syncthreads();
    if (jw < 4) {
        out[(size_t)T_STEPS * O_DIM + jw * 128 + 2 * lane] = tr0;
        out[(size_t)T_STEPS * O_DIM + jw * 128 + 2 * lane + 1] = tr1;
    }
}

extern "C" void kernel_launch(void* const* d_in, const int* in_sizes, int n_in,
                              void* d_out, int out_size, void* d_ws, size_t ws_size,
                              hipStream_t stream) {
    const float* spikes = (const float*)d_in[0];   // [T, I]
    const float* u_rand = (const float*)d_in[1];   // [T]
    const float* W      = (const float*)d_in[2];   // [O, I]
    const float* b      = (const float*)d_in[3];   // [O]
    float* out = (float*)d_out;                    // [T*O + O]

    float* Wrow = (float*)d_ws;                                        // 4 MB
    float* Wt   = Wrow + (size_t)O_DIM * I_DIM;                        // (I+1) x O
    unsigned short* idxl = (unsigned short*)(Wt + (size_t)(I_DIM + 1) * O_DIM);
    int* cnts = (int*)(idxl + (size_t)(T_STEPS + 4) * KPAD);

    hipMemsetAsync(d_out, 0, (size_t)out_size * sizeof(float), stream);

    hipLaunchKernelGGL(build_idx_kernel, dim3(T_STEPS + 4), dim3(256), 0, stream,
                       spikes, idxl, cnts);
    hipLaunchKernelGGL(copy_w_kernel, dim3((O_DIM * I_DIM / 4) / 256), dim3(256), 0, stream,
                       W, Wrow);
    hipLaunchKernelGGL(transpose_kernel, dim3(I_DIM / 32, O_DIM / 32), dim3(32, 8), 0, stream,
                       W, Wt);
    hipLaunchKernelGGL(zero_pad_row_kernel, dim3(1), dim3(O_DIM), 0, stream, Wt);
    hipLaunchKernelGGL(seq_kernel, dim3(1), dim3(WGS), 0, stream,
                       idxl, cnts, u_rand, b, Wrow, Wt, out);
}